// Round 1
// baseline (4418.543 us; speedup 1.0000x reference)
//
#include <hip/hip_runtime.h>
#include <hip/hip_bf16.h>

#define NORM_EPS_F 1e-6f
#define COS_EPS_F  1e-8f

__device__ __forceinline__ void atomAddF(float* p, float v) {
    // Hardware global_atomic_add_f32 regardless of -munsafe-fp-atomics.
    unsafeAtomicAdd(p, v);
}

// One thread per face: compute face normal for both meshes (shared index
// loads), scatter-add into per-vertex normal accumulators. 18 atomics/thread.
__global__ void __launch_bounds__(256) face_normals_kernel(
    const float* __restrict__ Vr, const float* __restrict__ Vg,
    const int* __restrict__ faces,
    float* __restrict__ vn_rec, float* __restrict__ vn_gt, int F)
{
    int f = blockIdx.x * blockDim.x + threadIdx.x;
    if (f >= F) return;
    int i0 = faces[3 * f + 0];
    int i1 = faces[3 * f + 1];
    int i2 = faces[3 * f + 2];

    // --- reconstructed mesh ---
    {
        float v0x = Vr[3 * i0 + 0], v0y = Vr[3 * i0 + 1], v0z = Vr[3 * i0 + 2];
        float v1x = Vr[3 * i1 + 0], v1y = Vr[3 * i1 + 1], v1z = Vr[3 * i1 + 2];
        float v2x = Vr[3 * i2 + 0], v2y = Vr[3 * i2 + 1], v2z = Vr[3 * i2 + 2];
        float ax = v1x - v0x, ay = v1y - v0y, az = v1z - v0z;
        float bx = v2x - v0x, by = v2y - v0y, bz = v2z - v0z;
        float nx = ay * bz - az * by;
        float ny = az * bx - ax * bz;
        float nz = ax * by - ay * bx;
        atomAddF(&vn_rec[3 * i0 + 0], nx); atomAddF(&vn_rec[3 * i0 + 1], ny); atomAddF(&vn_rec[3 * i0 + 2], nz);
        atomAddF(&vn_rec[3 * i1 + 0], nx); atomAddF(&vn_rec[3 * i1 + 1], ny); atomAddF(&vn_rec[3 * i1 + 2], nz);
        atomAddF(&vn_rec[3 * i2 + 0], nx); atomAddF(&vn_rec[3 * i2 + 1], ny); atomAddF(&vn_rec[3 * i2 + 2], nz);
    }
    // --- ground-truth mesh ---
    {
        float v0x = Vg[3 * i0 + 0], v0y = Vg[3 * i0 + 1], v0z = Vg[3 * i0 + 2];
        float v1x = Vg[3 * i1 + 0], v1y = Vg[3 * i1 + 1], v1z = Vg[3 * i1 + 2];
        float v2x = Vg[3 * i2 + 0], v2y = Vg[3 * i2 + 1], v2z = Vg[3 * i2 + 2];
        float ax = v1x - v0x, ay = v1y - v0y, az = v1z - v0z;
        float bx = v2x - v0x, by = v2y - v0y, bz = v2z - v0z;
        float nx = ay * bz - az * by;
        float ny = az * bx - ax * bz;
        float nz = ax * by - ay * bx;
        atomAddF(&vn_gt[3 * i0 + 0], nx); atomAddF(&vn_gt[3 * i0 + 1], ny); atomAddF(&vn_gt[3 * i0 + 2], nz);
        atomAddF(&vn_gt[3 * i1 + 0], nx); atomAddF(&vn_gt[3 * i1 + 1], ny); atomAddF(&vn_gt[3 * i1 + 2], nz);
        atomAddF(&vn_gt[3 * i2 + 0], nx); atomAddF(&vn_gt[3 * i2 + 1], ny); atomAddF(&vn_gt[3 * i2 + 2], nz);
    }
}

// One thread per nnz: delta[row] += val * V[col], both meshes fused
// (shared row/col/val loads and gather addresses). 6 atomics/thread.
__global__ void __launch_bounds__(256) spmm_kernel(
    const float* __restrict__ Vr, const float* __restrict__ Vg,
    const int* __restrict__ rows, const int* __restrict__ cols,
    const float* __restrict__ vals,
    float* __restrict__ dl_rec, float* __restrict__ dl_gt, int nnz)
{
    int i = blockIdx.x * blockDim.x + threadIdx.x;
    if (i >= nnz) return;
    int r = rows[i];
    int c = cols[i];
    float v = vals[i];
    float rx = Vr[3 * c + 0], ry = Vr[3 * c + 1], rz = Vr[3 * c + 2];
    float gx = Vg[3 * c + 0], gy = Vg[3 * c + 1], gz = Vg[3 * c + 2];
    atomAddF(&dl_rec[3 * r + 0], v * rx);
    atomAddF(&dl_rec[3 * r + 1], v * ry);
    atomAddF(&dl_rec[3 * r + 2], v * rz);
    atomAddF(&dl_gt[3 * r + 0], v * gx);
    atomAddF(&dl_gt[3 * r + 1], v * gy);
    atomAddF(&dl_gt[3 * r + 2], v * gz);
}

// One thread per vertex: l1 partial, normal-cos partial, laplacian-cos
// partial, nonfinite count. Block-reduce -> 1 atomic per component per block.
__global__ void __launch_bounds__(256) reduce_kernel(
    const float* __restrict__ Vr, const float* __restrict__ Vg,
    const float* __restrict__ vn_rec, const float* __restrict__ vn_gt,
    const float* __restrict__ dl_rec, const float* __restrict__ dl_gt,
    float* __restrict__ accum, int N)
{
    int i = blockIdx.x * blockDim.x + threadIdx.x;
    float l1 = 0.0f, ln = 0.0f, ll = 0.0f, nonfin = 0.0f;
    if (i < N) {
        // --- L1 ---
        float rx = Vr[3 * i + 0], ry = Vr[3 * i + 1], rz = Vr[3 * i + 2];
        float gx = Vg[3 * i + 0], gy = Vg[3 * i + 1], gz = Vg[3 * i + 2];
        l1 = fabsf(rx - gx) + fabsf(ry - gy) + fabsf(rz - gz);

        // --- normal cosine (replicates reference: normalize, then cos) ---
        float ax = vn_rec[3 * i + 0], ay = vn_rec[3 * i + 1], az = vn_rec[3 * i + 2];
        float bx = vn_gt[3 * i + 0],  by = vn_gt[3 * i + 1],  bz = vn_gt[3 * i + 2];
        float na = sqrtf(ax * ax + ay * ay + az * az);
        float nb = sqrtf(bx * bx + by * by + bz * bz);
        float ia = 1.0f / fmaxf(na, NORM_EPS_F);
        float ib = 1.0f / fmaxf(nb, NORM_EPS_F);
        ax *= ia; ay *= ia; az *= ia;
        bx *= ib; by *= ib; bz *= ib;
        float dot = ax * bx + ay * by + az * bz;
        float nna = sqrtf(ax * ax + ay * ay + az * az);
        float nnb = sqrtf(bx * bx + by * by + bz * bz);
        float cosn = dot / (fmaxf(nna, COS_EPS_F) * fmaxf(nnb, COS_EPS_F));
        if (isnan(cosn)) cosn = 1.0f;
        ln = 1.0f - cosn;

        // --- laplacian cosine ---
        float px = dl_rec[3 * i + 0], py = dl_rec[3 * i + 1], pz = dl_rec[3 * i + 2];
        float qx = dl_gt[3 * i + 0],  qy = dl_gt[3 * i + 1],  qz = dl_gt[3 * i + 2];
        bool fin = isfinite(px) && isfinite(py) && isfinite(pz) &&
                   isfinite(qx) && isfinite(qy) && isfinite(qz);
        nonfin = fin ? 0.0f : 1.0f;
        float dotl = px * qx + py * qy + pz * qz;
        float npn = sqrtf(px * px + py * py + pz * pz);
        float nqn = sqrtf(qx * qx + qy * qy + qz * qz);
        float cosl = dotl / (fmaxf(npn, COS_EPS_F) * fmaxf(nqn, COS_EPS_F));
        if (isnan(cosl)) cosl = 1.0f;
        ll = 1.0f - cosl;
    }

    // wave64 butterfly
    for (int off = 32; off > 0; off >>= 1) {
        l1     += __shfl_down(l1, off, 64);
        ln     += __shfl_down(ln, off, 64);
        ll     += __shfl_down(ll, off, 64);
        nonfin += __shfl_down(nonfin, off, 64);
    }
    __shared__ float s[4][4];
    int wave = threadIdx.x >> 6;
    int lane = threadIdx.x & 63;
    if (lane == 0) {
        s[wave][0] = l1; s[wave][1] = ln; s[wave][2] = ll; s[wave][3] = nonfin;
    }
    __syncthreads();
    if (threadIdx.x == 0) {
        float a = 0.0f, b = 0.0f, c = 0.0f, d = 0.0f;
        int nw = (blockDim.x + 63) >> 6;
        for (int w = 0; w < nw; ++w) {
            a += s[w][0]; b += s[w][1]; c += s[w][2]; d += s[w][3];
        }
        atomAddF(&accum[0], a);
        atomAddF(&accum[1], b);
        atomAddF(&accum[2], c);
        atomAddF(&accum[3], d);
    }
}

__global__ void finalize_kernel(const float* __restrict__ accum,
                                float* __restrict__ out, int N)
{
    float invN = 1.0f / (float)N;
    float l1 = accum[0] * invN * (1.0f / 3.0f);
    float ln = accum[1] * invN;
    float ll = (accum[3] > 0.0f) ? 0.0f : accum[2] * invN;
    out[0] = 1.0f * l1 + 1.0f * ln + 0.1f * ll;
}

extern "C" void kernel_launch(void* const* d_in, const int* in_sizes, int n_in,
                              void* d_out, int out_size, void* d_ws, size_t ws_size,
                              hipStream_t stream)
{
    const float* Vr    = (const float*)d_in[0];
    const float* Vg    = (const float*)d_in[1];
    const int*   faces = (const int*)d_in[2];
    const int*   Lr    = (const int*)d_in[3];
    const int*   Lc    = (const int*)d_in[4];
    const float* Lv    = (const float*)d_in[5];

    const int N   = in_sizes[0] / 3;
    const int F   = in_sizes[2] / 3;
    const int NNZ = in_sizes[3];

    float* ws     = (float*)d_ws;
    float* vn_rec = ws;
    float* vn_gt  = ws + (size_t)3 * N;
    float* dl_rec = ws + (size_t)6 * N;
    float* dl_gt  = ws + (size_t)9 * N;
    float* accum  = ws + (size_t)12 * N;

    // Zero scatter targets + accumulators (ws is poisoned 0xAA every call).
    hipMemsetAsync(d_ws, 0, ((size_t)12 * N + 4) * sizeof(float), stream);

    const int B = 256;
    face_normals_kernel<<<dim3((F + B - 1) / B), dim3(B), 0, stream>>>(
        Vr, Vg, faces, vn_rec, vn_gt, F);
    spmm_kernel<<<dim3((NNZ + B - 1) / B), dim3(B), 0, stream>>>(
        Vr, Vg, Lr, Lc, Lv, dl_rec, dl_gt, NNZ);
    reduce_kernel<<<dim3((N + B - 1) / B), dim3(B), 0, stream>>>(
        Vr, Vg, vn_rec, vn_gt, dl_rec, dl_gt, accum, N);
    finalize_kernel<<<dim3(1), dim3(1), 0, stream>>>(accum, (float*)d_out, N);
}